// Round 6
// baseline (993.387 us; speedup 1.0000x reference)
//
#include <hip/hip_runtime.h>

typedef __bf16 bf16x8 __attribute__((ext_vector_type(8)));
typedef __bf16 bf16x4 __attribute__((ext_vector_type(4)));
typedef float  f32x4  __attribute__((ext_vector_type(4)));

#define NB 8
#define NC 64
#define NH 256
#define NW 256
#define NT 16     // W tiles
#define WT 16     // core width per WG
#define SEG 32    // steps between neighbor syncs == halo width per side
#define NS 5      // window subtiles: (WT + 2*SEG)/16
#define LDSW 82   // window + conv pad columns, w = wc0-1 .. wc0+80
#define LDSC 72   // ci stride: 144 B rows keep ds_read_b128 16B-aligned

// tanh(x) = 1 - 2/(1+e^{2x}); bounded, branch-free, NaN-free for finite x
__device__ __forceinline__ float fast_tanh(float x) {
    float e = __expf(2.0f * x);
    return 1.0f - 2.0f / (1.0f + e);
}

// 128 WGs = 8 batches x 16 W-tiles, 4 waves each (1 wave/SIMD) -- the
// verified SEG=32 structure (580us), with the wave<->work mapping inverted
// to cut LDS-read redundancy 2.5x:
//   OLD: wave = co-tile; each wave read the whole 80-col window x3 taps
//        (30 ds_read_b128/wave, 120/CU/step).
//   NEW: wave = w-subtile; each wave holds ALL 64 co weights in VGPRs
//        (afrag[4][6], 96 regs) and reads ONLY its subtile s=wv (6 b128)
//        plus the shared 5th subtile s=4 (6 b128) -> 48 reads/CU/step.
// MFMA count (30/wave), tanh count (20/lane), X/Y traffic, and the exact
// per-output arithmetic chain are unchanged -> bitwise-identical numerics.
__global__ __launch_bounds__(256, 1)
void spconv_trap(const float* __restrict__ Xg,
                 const float* __restrict__ Wg,
                 const float* __restrict__ Bg,
                 float* __restrict__ Yg,
                 int* __restrict__ flags)
{
    const int b    = blockIdx.x & 7;
    const int t    = blockIdx.x >> 3;
    const int tid  = threadIdx.x;
    const int wv   = tid >> 6;     // 0..3: wave = primary w-subtile
    const int lane = tid & 63;
    const int g    = lane >> 4;    // quad
    const int lm   = lane & 15;
    const int w0   = t * WT;
    const int wc0  = w0 - SEG;     // window start

    __shared__ __bf16 buf[2][LDSW][LDSC];  // double-buffered prev row, 23.6 KB

    // ---- ALL co-tiles' A fragments resident in VGPRs ----
    // chunk c: k-tap = c>>1, ci0 = 32*(c&1)+8g; A[m=lm][q=8g+j]=W[co][ci0+j][k]
    bf16x8 afrag[4][6];
    #pragma unroll
    for (int ct = 0; ct < 4; ++ct) {
        const int co = ct * 16 + lm;
        #pragma unroll
        for (int c = 0; c < 6; ++c) {
            const int k = c >> 1, ci0 = 32 * (c & 1) + 8 * g;
            bf16x8 a;
            #pragma unroll
            for (int j = 0; j < 8; ++j)
                a[j] = (__bf16)Wg[(co * NC + ci0 + j) * 3 + k];
            afrag[ct][c] = a;
        }
    }
    float bias_r[4][4];
    #pragma unroll
    for (int ct = 0; ct < 4; ++ct)
        #pragma unroll
        for (int i = 0; i < 4; ++i)
            bias_r[ct][i] = Bg[ct * 16 + 4 * g + i];

    // ---- init: BOTH buffers <- X row 0 over the window (clamped outside) ----
    {
        const int ci = tid & 63;
        for (int r = (tid >> 6); r < LDSW; r += 4) {
            const int w = wc0 - 1 + r;
            float v = (w >= 0 && w < NW)
                    ? Xg[((size_t)(b * NC + ci) * NH + 0) * NW + w] : 0.0f;
            const __bf16 bv = (__bf16)v;
            buf[0][r][ci] = bv;
            buf[1][r][ci] = bv;
        }
    }
    // Y row 0 = X row 0 (exact fp32 passthrough), core columns only
    #pragma unroll
    for (int i = 0; i < 4; ++i) {
        const int co = wv * 16 + 4 * g + i;
        const size_t idx = ((size_t)(b * NC + co) * NH + 0) * NW + w0 + lm;
        Yg[idx] = Xg[idx];
    }

    // per-lane window columns: primary (s=wv) and secondary (s=4)
    const int wp = wc0 + 16 * wv + lm;
    const int ws = wc0 + 64 + lm;
    const bool wokp = (wp >= 0 && wp < NW);
    const bool woks = (ws >= 0 && ws < NW);

    // ping-pong X prefetch registers; preload row 1 into xA
    // [ct][i]: primary subtile, co = 16ct+4g+i; [4][i]: secondary, co = 16wv+4g+i
    float xA[5][4], xB[5][4];
    #pragma unroll
    for (int ct = 0; ct < 4; ++ct)
        #pragma unroll
        for (int i = 0; i < 4; ++i) {
            const int co = ct * 16 + 4 * g + i;
            xA[ct][i] = wokp
                ? Xg[((size_t)(b * NC + co) * NH + 1) * NW + wp] : 0.0f;
        }
    #pragma unroll
    for (int i = 0; i < 4; ++i) {
        const int co = wv * 16 + 4 * g + i;
        xA[4][i] = woks
            ? Xg[((size_t)(b * NC + co) * NH + 1) * NW + ws] : 0.0f;
    }
    __syncthreads();

    const int myflag = b * NT + t;

    // p is a compile-time constant at each call site (body inlined twice per
    // unrolled pair), so LDS buffer selection folds to immediates.
    auto body = [&](int h, int p, float (&xcur)[5][4], float (&xnext)[5][4]) {
        // ---- prefetch X[h+1] at step top: ~1 full step to cover HBM ----
        if (h + 1 < NH) {
            #pragma unroll
            for (int ct = 0; ct < 4; ++ct)
                #pragma unroll
                for (int i = 0; i < 4; ++i) {
                    const int co = ct * 16 + 4 * g + i;
                    xnext[ct][i] = wokp
                        ? Xg[((size_t)(b * NC + co) * NH + h + 1) * NW + wp] : 0.0f;
                }
            #pragma unroll
            for (int i = 0; i < 4; ++i) {
                const int co = wv * 16 + 4 * g + i;
                xnext[4][i] = woks
                    ? Xg[((size_t)(b * NC + co) * NH + h + 1) * NW + ws] : 0.0f;
            }
        }

        // ---- LDS reads: ONLY this wave's subtiles (6 + 6 ds_read_b128) ----
        bf16x8 bfrp[6], bfrs[6];
        #pragma unroll
        for (int c = 0; c < 6; ++c)
            bfrp[c] = *(const bf16x8*)
                &buf[p][16 * wv + lm + (c >> 1)][32 * (c & 1) + 8 * g];
        #pragma unroll
        for (int c = 0; c < 6; ++c)
            bfrs[c] = *(const bf16x8*)
                &buf[p][64 + lm + (c >> 1)][32 * (c & 1) + 8 * g];

        // ---- conv: primary subtile x 4 co-tiles + secondary x 1 co-tile ----
        float yp[4][4], ys[4];
        #pragma unroll
        for (int ct = 0; ct < 4; ++ct) {
            f32x4 acc = {0.f, 0.f, 0.f, 0.f};
            #pragma unroll
            for (int c = 0; c < 6; ++c)
                acc = __builtin_amdgcn_mfma_f32_16x16x32_bf16(
                        afrag[ct][c], bfrp[c], acc, 0, 0, 0);
            #pragma unroll
            for (int i = 0; i < 4; ++i)
                yp[ct][i] = xcur[ct][i] + fast_tanh(acc[i] + bias_r[ct][i]);
        }
        {
            f32x4 acc = {0.f, 0.f, 0.f, 0.f};
            #pragma unroll
            for (int c = 0; c < 6; ++c)
                acc = __builtin_amdgcn_mfma_f32_16x16x32_bf16(
                        afrag[wv][c], bfrs[c], acc, 0, 0, 0);
            #pragma unroll
            for (int i = 0; i < 4; ++i)
                ys[i] = xcur[4][i] + fast_tanh(acc[i] + bias_r[wv][i]);
        }

        // ---- store core columns to global: wave 2 owns s=2 (wp == w0+lm) ----
        if (wv == 2) {
            #pragma unroll
            for (int ct = 0; ct < 4; ++ct)
                #pragma unroll
                for (int i = 0; i < 4; ++i) {
                    const int co = ct * 16 + 4 * g + i;
                    Yg[((size_t)(b * NC + co) * NH + h) * NW + w0 + lm] = yp[ct][i];
                }
        }

        // ---- write new row into the OTHER buffer (no read-WAR barrier) ----
        #pragma unroll
        for (int ct = 0; ct < 4; ++ct) {
            bf16x4 pk;
            #pragma unroll
            for (int i = 0; i < 4; ++i)
                pk[i] = wokp ? (__bf16)yp[ct][i] : (__bf16)0.0f;
            *(bf16x4*)&buf[p ^ 1][16 * wv + lm + 1][ct * 16 + 4 * g] = pk;
        }
        {
            bf16x4 pk;
            #pragma unroll
            for (int i = 0; i < 4; ++i)
                pk[i] = woks ? (__bf16)ys[i] : (__bf16)0.0f;
            *(bf16x4*)&buf[p ^ 1][64 + lm + 1][wv * 16 + 4 * g] = pk;
        }

        const bool boundary = (h < NH - 1) && ((h & (SEG - 1)) == 0);
        if (boundary) {
            const int k = h >> 5;          // completed segment index, 1..7
            __threadfence();               // publish my Y stores (drains vmcnt)
            __syncthreads();               // all fences done before flag store
            if (tid == 0)
                __hip_atomic_store(&flags[myflag], k,
                                   __ATOMIC_RELEASE, __HIP_MEMORY_SCOPE_AGENT);
            // spin in two different waves so the waits overlap
            if (t > 0 && tid == 32) {
                while (__hip_atomic_load(&flags[myflag - 1], __ATOMIC_ACQUIRE,
                                         __HIP_MEMORY_SCOPE_AGENT) < k)
                    __builtin_amdgcn_s_sleep(2);
            }
            if (t < NT - 1 && tid == 96) {
                while (__hip_atomic_load(&flags[myflag + 1], __ATOMIC_ACQUIRE,
                                         __HIP_MEMORY_SCOPE_AGENT) < k)
                    __builtin_amdgcn_s_sleep(2);
            }
            __syncthreads();
            // refill halo regions of buf[p^1] from neighbors' Y[h]
            // left: rows 1..32 (w = w0-32..w0-1); right: rows 49..80
            for (int idx = tid; idx < 2 * SEG * NC; idx += 256) {
                const int wloc = idx & 31;
                const int ci   = (idx >> 5) & 63;
                const int side = idx >> 11;            // 0 = left, 1 = right
                const bool have = side ? (t < NT - 1) : (t > 0);
                if (have) {
                    const int w = w0 - SEG + wloc + side * (WT + SEG);
                    const int r = wloc + 1 + side * (WT + SEG);
                    buf[p ^ 1][r][ci] =
                        (__bf16)Yg[((size_t)(b * NC + ci) * NH + h) * NW + w];
                }
            }
            __syncthreads();
        } else {
            // LDS-only barrier: new-row ds_writes visible, vmcnt NOT drained
            asm volatile("s_waitcnt lgkmcnt(0)" ::: "memory");
            __builtin_amdgcn_sched_barrier(0);
            __builtin_amdgcn_s_barrier();
            __builtin_amdgcn_sched_barrier(0);
        }
    };

    // h odd -> reads buf[0], writes buf[1]; h even -> the reverse.
    // Boundaries (h % 32 == 0) always land in the second body (p = 1).
    for (int h = 1; h < NH; h += 2) {
        body(h, 0, xA, xB);
        if (h + 1 < NH) body(h + 1, 1, xB, xA);
    }
}

extern "C" void kernel_launch(void* const* d_in, const int* in_sizes, int n_in,
                              void* d_out, int out_size, void* d_ws, size_t ws_size,
                              hipStream_t stream)
{
    const float* X  = (const float*)d_in[0];
    const float* Wc = (const float*)d_in[1];
    const float* Bc = (const float*)d_in[2];
    float* Y        = (float*)d_out;
    int* flags      = (int*)d_ws;   // 128 ints; d_ws is poisoned 0xAA -> memset

    hipMemsetAsync(d_ws, 0, NB * NT * sizeof(int), stream);

    dim3 grid(NB * NT);   // 128 WGs x 4 waves: all co-resident, spin-safe
    dim3 block(256);
    hipLaunchKernelGGL(spconv_trap, grid, block, 0, stream, X, Wc, Bc, Y, flags);
}

// Round 7
// 618.443 us; speedup vs baseline: 1.6063x; 1.6063x over previous
//
#include <hip/hip_runtime.h>

typedef __bf16 bf16x8 __attribute__((ext_vector_type(8)));
typedef __bf16 bf16x4 __attribute__((ext_vector_type(4)));
typedef float  f32x4  __attribute__((ext_vector_type(4)));

#define NB 8
#define NC 64
#define NH 256
#define NW 256
#define NT 16     // W tiles
#define WT 16     // core width per WG
#define SEG 32    // steps between neighbor syncs == halo width per side
#define NS 5      // window subtiles: (WT + 2*SEG)/16
#define LDSW 82   // window + conv pad columns, w = wc0-1 .. wc0+80
#define LDSC 72   // ci stride: 144 B rows keep ds_read_b128 16B-aligned

// tanh(x) = 1 - 2/(1+e^{2x}), with the division replaced by v_rcp_f32
// (<=1 ulp): without fast-math, "2.0f/(1.0f+e)" lowers to the full IEEE
// div_scale/rcp/Newton/div_fixup sequence (~10 instrs, several quarter-rate)
// -- at 20 outputs/lane/step that sequence was the largest single step cost.
// rcp error ~2^-22 is far below the bf16 rounding already in the recurrence.
__device__ __forceinline__ float fast_tanh(float x) {
    float e = __expf(2.0f * x);
    return 1.0f - 2.0f * __builtin_amdgcn_rcpf(1.0f + e);
}

// 128 WGs = 8 batches x 16 W-tiles; blockIdx&7 = batch -> same-batch tiles
// share an XCD. Each WG computes an 80-wide trapezoid window (16 core +
// 32 halo each side); neighbor halo exchange through global Y every SEG=32
// steps. Halo validity erodes one column per side per step, so after 32
// steps exactly the 16-wide core is still exact. Wave = co-tile (all LDS
// array indices compile-time; no runtime-indexed register arrays).
__global__ __launch_bounds__(256, 1)
void spconv_trap(const float* __restrict__ Xg,
                 const float* __restrict__ Wg,
                 const float* __restrict__ Bg,
                 float* __restrict__ Yg,
                 int* __restrict__ flags)
{
    const int b    = blockIdx.x & 7;
    const int t    = blockIdx.x >> 3;
    const int tid  = threadIdx.x;
    const int wv   = tid >> 6;     // 0..3: wave = co-tile
    const int lane = tid & 63;
    const int g    = lane >> 4;    // quad
    const int lm   = lane & 15;
    const int w0   = t * WT;
    const int wc0  = w0 - SEG;     // window start

    __shared__ __bf16 buf[2][LDSW][LDSC];  // double-buffered prev row, 23.6 KB

    // ---- A fragments (this wave's co-tile only), resident in VGPRs ----
    // chunk c: k-tap = c>>1, ci0 = 32*(c&1)+8g; A[m=lm][q=8g+j]=W[co][ci0+j][k]
    bf16x8 afrag[6];
    {
        const int co = wv * 16 + lm;
        #pragma unroll
        for (int c = 0; c < 6; ++c) {
            const int k = c >> 1, ci0 = 32 * (c & 1) + 8 * g;
            bf16x8 a;
            #pragma unroll
            for (int j = 0; j < 8; ++j)
                a[j] = (__bf16)Wg[(co * NC + ci0 + j) * 3 + k];
            afrag[c] = a;
        }
    }
    float bias_r[4];
    #pragma unroll
    for (int i = 0; i < 4; ++i)
        bias_r[i] = Bg[wv * 16 + 4 * g + i];

    // ---- init: BOTH buffers <- X row 0 over the window (clamped outside) ----
    {
        const int ci = tid & 63;
        for (int r = (tid >> 6); r < LDSW; r += 4) {
            const int w = wc0 - 1 + r;
            float v = (w >= 0 && w < NW)
                    ? Xg[((size_t)(b * NC + ci) * NH + 0) * NW + w] : 0.0f;
            const __bf16 bv = (__bf16)v;
            buf[0][r][ci] = bv;
            buf[1][r][ci] = bv;
        }
    }
    // Y row 0 = X row 0 (exact fp32 passthrough), core columns only
    #pragma unroll
    for (int i = 0; i < 4; ++i) {
        const int co = wv * 16 + 4 * g + i;
        const size_t idx = ((size_t)(b * NC + co) * NH + 0) * NW + w0 + lm;
        Yg[idx] = Xg[idx];
    }

    // per-lane window columns and validity (fixed for the whole kernel)
    bool wok[NS];
    #pragma unroll
    for (int s = 0; s < NS; ++s) {
        const int w = wc0 + 16 * s + lm;
        wok[s] = (w >= 0 && w < NW);
    }

    // ping-pong X prefetch registers; preload row 1 into xA
    float xA[NS][4], xB[NS][4];
    #pragma unroll
    for (int s = 0; s < NS; ++s)
        #pragma unroll
        for (int i = 0; i < 4; ++i) {
            const int co = wv * 16 + 4 * g + i;
            const int w  = wc0 + 16 * s + lm;
            xA[s][i] = wok[s]
                ? Xg[((size_t)(b * NC + co) * NH + 1) * NW + w] : 0.0f;
        }
    __syncthreads();

    const int myflag = b * NT + t;

    // p is a compile-time constant at each call site (body inlined twice per
    // unrolled pair), so all LDS bases fold to immediates.
    auto body = [&](int h, int p, float (&xcur)[NS][4], float (&xnext)[NS][4]) {
        // ---- prefetch X[h+1] at step top: ~1 full step to cover HBM ----
        if (h + 1 < NH) {
            #pragma unroll
            for (int s = 0; s < NS; ++s)
                #pragma unroll
                for (int i = 0; i < 4; ++i) {
                    const int co = wv * 16 + 4 * g + i;
                    const int w  = wc0 + 16 * s + lm;
                    xnext[s][i] = wok[s]
                        ? Xg[((size_t)(b * NC + co) * NH + h + 1) * NW + w] : 0.0f;
                }
        }

        // ---- conv over NS w-subtiles from buf[p]: D = sum_c A_c*B_c, K=192 ----
        float yv[NS][4];
        #pragma unroll
        for (int s = 0; s < NS; ++s) {
            f32x4 acc = {0.f, 0.f, 0.f, 0.f};
            #pragma unroll
            for (int c = 0; c < 6; ++c) {
                const bf16x8 bfr =
                    *(const bf16x8*)&buf[p][16 * s + lm + (c >> 1)][32 * (c & 1) + 8 * g];
                acc = __builtin_amdgcn_mfma_f32_16x16x32_bf16(afrag[c], bfr, acc, 0, 0, 0);
            }
            #pragma unroll
            for (int i = 0; i < 4; ++i)
                yv[s][i] = xcur[s][i] + fast_tanh(acc[i] + bias_r[i]);
        }
        // ---- store core columns (subtile SEG/16 = 2) to global, fp32 ----
        #pragma unroll
        for (int i = 0; i < 4; ++i) {
            const int co = wv * 16 + 4 * g + i;
            Yg[((size_t)(b * NC + co) * NH + h) * NW + w0 + lm] = yv[SEG / 16][i];
        }

        // ---- write new row into the OTHER buffer (no read-WAR barrier) ----
        #pragma unroll
        for (int s = 0; s < NS; ++s) {
            bf16x4 pk;
            #pragma unroll
            for (int i = 0; i < 4; ++i)
                pk[i] = wok[s] ? (__bf16)yv[s][i] : (__bf16)0.0f;
            *(bf16x4*)&buf[p ^ 1][16 * s + lm + 1][wv * 16 + 4 * g] = pk;
        }

        const bool boundary = (h < NH - 1) && ((h & (SEG - 1)) == 0);
        if (boundary) {
            const int k = h >> 5;          // completed segment index, 1..7
            __threadfence();               // publish my Y stores (drains vmcnt)
            __syncthreads();               // all fences done before flag store
            if (tid == 0)
                __hip_atomic_store(&flags[myflag], k,
                                   __ATOMIC_RELEASE, __HIP_MEMORY_SCOPE_AGENT);
            // spin in two different waves so the waits overlap
            if (t > 0 && tid == 32) {
                while (__hip_atomic_load(&flags[myflag - 1], __ATOMIC_ACQUIRE,
                                         __HIP_MEMORY_SCOPE_AGENT) < k)
                    __builtin_amdgcn_s_sleep(2);
            }
            if (t < NT - 1 && tid == 96) {
                while (__hip_atomic_load(&flags[myflag + 1], __ATOMIC_ACQUIRE,
                                         __HIP_MEMORY_SCOPE_AGENT) < k)
                    __builtin_amdgcn_s_sleep(2);
            }
            __syncthreads();
            // refill halo regions of buf[p^1] from neighbors' Y[h], f32x4:
            // 2 sides x 64 ci x 8 w-quads = 1024 tasks, 4 per thread
            for (int idx = tid; idx < 2 * NC * (SEG / 4); idx += 256) {
                const int q8   = idx & 7;
                const int ci   = (idx >> 3) & 63;
                const int side = idx >> 9;             // 0 = left, 1 = right
                const bool have = side ? (t < NT - 1) : (t > 0);
                if (have) {
                    const int wq = w0 - SEG + 4 * q8 + side * (WT + SEG);
                    const int r  = 4 * q8 + 1 + side * (WT + SEG);
                    const f32x4 v = *(const f32x4*)
                        &Yg[((size_t)(b * NC + ci) * NH + h) * NW + wq];
                    #pragma unroll
                    for (int i2 = 0; i2 < 4; ++i2)
                        buf[p ^ 1][r + i2][ci] = (__bf16)v[i2];
                }
            }
            __syncthreads();
        } else {
            // LDS-only barrier: new-row ds_writes visible, vmcnt NOT drained
            asm volatile("s_waitcnt lgkmcnt(0)" ::: "memory");
            __builtin_amdgcn_sched_barrier(0);
            __builtin_amdgcn_s_barrier();
            __builtin_amdgcn_sched_barrier(0);
        }
    };

    // h odd -> reads buf[0], writes buf[1]; h even -> the reverse.
    // Boundaries (h % 32 == 0) always land in the second body (p = 1).
    for (int h = 1; h < NH; h += 2) {
        body(h, 0, xA, xB);
        if (h + 1 < NH) body(h + 1, 1, xB, xA);
    }
}

extern "C" void kernel_launch(void* const* d_in, const int* in_sizes, int n_in,
                              void* d_out, int out_size, void* d_ws, size_t ws_size,
                              hipStream_t stream)
{
    const float* X  = (const float*)d_in[0];
    const float* Wc = (const float*)d_in[1];
    const float* Bc = (const float*)d_in[2];
    float* Y        = (float*)d_out;
    int* flags      = (int*)d_ws;   // 128 ints; d_ws is poisoned 0xAA -> memset

    hipMemsetAsync(d_ws, 0, NB * NT * sizeof(int), stream);

    dim3 grid(NB * NT);   // 128 WGs x 4 waves: all co-resident, spin-safe
    dim3 block(256);
    hipLaunchKernelGGL(spconv_trap, grid, block, 0, stream, X, Wc, Bc, Y, flags);
}